// Round 1
// baseline (1013.690 us; speedup 1.0000x reference)
//
#include <hip/hip_runtime.h>

#define D 128
#define TPAD 132

// ---------------- CSR build ----------------

__global__ __launch_bounds__(256) void zero_int(int* __restrict__ p, int n) {
    int i = blockIdx.x * 256 + threadIdx.x;
    if (i < n) p[i] = 0;
}

__global__ __launch_bounds__(256) void hist_kernel(const int* __restrict__ dst,
                                                   int* __restrict__ cnt, int E) {
    int e = blockIdx.x * 256 + threadIdx.x;
    if (e < E) atomicAdd(&cnt[dst[e]], 1);
}

__global__ __launch_bounds__(256) void dis_kernel(const int* __restrict__ cnt,
                                                  float* __restrict__ dis, int n) {
    int i = blockIdx.x * 256 + threadIdx.x;
    if (i < n) dis[i] = rsqrtf((float)(cnt[i] + 1));   // +1 self-loop; deg>=1 always
}

__global__ __launch_bounds__(256) void scan1_kernel(const int* __restrict__ cnt,
                                                    int* __restrict__ row_ptr,
                                                    int* __restrict__ bsum, int n) {
    __shared__ int sh[256];
    int t = threadIdx.x;
    int i = blockIdx.x * 256 + t;
    int v = (i < n) ? cnt[i] : 0;
    sh[t] = v;
    __syncthreads();
    for (int off = 1; off < 256; off <<= 1) {
        int add = (t >= off) ? sh[t - off] : 0;
        __syncthreads();
        sh[t] += add;
        __syncthreads();
    }
    if (i < n) row_ptr[i] = sh[t] - v;       // block-local exclusive
    if (t == 255) bsum[blockIdx.x] = sh[255];
}

__global__ __launch_bounds__(512) void scan2_kernel(int* __restrict__ bsum, int nb) {
    __shared__ int sh[512];
    int t = threadIdx.x;
    int v = (t < nb) ? bsum[t] : 0;
    sh[t] = v;
    __syncthreads();
    for (int off = 1; off < 512; off <<= 1) {
        int add = (t >= off) ? sh[t - off] : 0;
        __syncthreads();
        sh[t] += add;
        __syncthreads();
    }
    if (t < nb) bsum[t] = sh[t] - v;         // exclusive scan of block sums
}

__global__ __launch_bounds__(256) void scan3_kernel(int* __restrict__ row_ptr,
                                                    int* __restrict__ row_cur,
                                                    const int* __restrict__ bsum,
                                                    int n, int E) {
    int i = blockIdx.x * 256 + threadIdx.x;
    if (i < n) {
        int v = row_ptr[i] + bsum[blockIdx.x];
        row_ptr[i] = v;
        row_cur[i] = v;
    }
    if (i == 0) row_ptr[n] = E;
}

__global__ __launch_bounds__(256) void scatter_kernel(const int* __restrict__ src,
                                                      const int* __restrict__ dst,
                                                      int* __restrict__ row_cur,
                                                      int* __restrict__ csr_src, int E) {
    int e = blockIdx.x * 256 + threadIdx.x;
    if (e < E) {
        int d = dst[e];
        int pos = atomicAdd(&row_cur[d], 1);
        csr_src[pos] = src[e];
    }
}

// ---------------- GEMM: C[n x 128] = (relu?)A[n x 128] @ W[128 x 128] ----------------
// 128-row tile per block, K chunked by 32. A stored k-major (transposed) in LDS so
// the 8-row fragment reads are contiguous ds_read_b128. PAD=132 keeps 16B alignment.

template <bool RELU>
__global__ __launch_bounds__(256, 2) void gemm_kernel(const float* __restrict__ A,
                                                      const float* __restrict__ W,
                                                      float* __restrict__ C, int n) {
    __shared__ float sAT[32 * TPAD];   // [k][r], 16.9 KB
    __shared__ float sW[32 * TPAD];    // [k][c], 16.9 KB
    int tid = threadIdx.x;
    int base = blockIdx.x * 128;
    int tx = tid & 15, ty = tid >> 4;

    float acc[8][8];
#pragma unroll
    for (int i = 0; i < 8; ++i)
#pragma unroll
        for (int j = 0; j < 8; ++j) acc[i][j] = 0.f;

    for (int kb = 0; kb < 128; kb += 32) {
        __syncthreads();   // protect previous chunk's reads
#pragma unroll
        for (int it = 0; it < 4; ++it) {
            int idx = it * 1024 + tid * 4;   // 0..4095
            // A: 128 rows x 32 ks, transposed store
            int r = idx >> 5, kk = idx & 31;
            int row = base + r;
            float4 va = make_float4(0.f, 0.f, 0.f, 0.f);
            if (row < n) va = *(const float4*)&A[row * D + kb + kk];
            if (RELU) {
                va.x = fmaxf(va.x, 0.f); va.y = fmaxf(va.y, 0.f);
                va.z = fmaxf(va.z, 0.f); va.w = fmaxf(va.w, 0.f);
            }
            sAT[(kk + 0) * TPAD + r] = va.x;
            sAT[(kk + 1) * TPAD + r] = va.y;
            sAT[(kk + 2) * TPAD + r] = va.z;
            sAT[(kk + 3) * TPAD + r] = va.w;
            // W: 32 ks x 128 cols, direct store
            int wk = idx >> 7, wc = idx & 127;
            *(float4*)&sW[wk * TPAD + wc] = *(const float4*)&W[(kb + wk) * D + wc];
        }
        __syncthreads();
#pragma unroll
        for (int k = 0; k < 32; ++k) {
            float4 a0 = *(const float4*)&sAT[k * TPAD + ty * 8];
            float4 a1 = *(const float4*)&sAT[k * TPAD + ty * 8 + 4];
            float4 w0 = *(const float4*)&sW[k * TPAD + tx * 8];
            float4 w1 = *(const float4*)&sW[k * TPAD + tx * 8 + 4];
            float a[8] = {a0.x, a0.y, a0.z, a0.w, a1.x, a1.y, a1.z, a1.w};
            float w[8] = {w0.x, w0.y, w0.z, w0.w, w1.x, w1.y, w1.z, w1.w};
#pragma unroll
            for (int i = 0; i < 8; ++i)
#pragma unroll
                for (int j = 0; j < 8; ++j) acc[i][j] = fmaf(a[i], w[j], acc[i][j]);
        }
    }

#pragma unroll
    for (int i = 0; i < 8; ++i) {
        int row = base + ty * 8 + i;
        if (row < n) {
            float4 o0 = make_float4(acc[i][0], acc[i][1], acc[i][2], acc[i][3]);
            float4 o1 = make_float4(acc[i][4], acc[i][5], acc[i][6], acc[i][7]);
            *(float4*)&C[row * D + tx * 8] = o0;
            *(float4*)&C[row * D + tx * 8 + 4] = o1;
        }
    }
}

// ---------------- Aggregation: out[i] = b + dis_i^2*H[i] + sum_e dis[s]*dis_i*H[s] ----

__global__ __launch_bounds__(128) void aggregate_kernel(const float* __restrict__ H,
                                                        const int* __restrict__ row_ptr,
                                                        const int* __restrict__ csr_src,
                                                        const float* __restrict__ dis,
                                                        const float* __restrict__ b,
                                                        float* __restrict__ out, int n) {
    int node = blockIdx.x;
    int c = threadIdx.x;
    float di = dis[node];
    float acc = di * di * H[(size_t)node * D + c];   // self-loop
    int p0 = row_ptr[node], p1 = row_ptr[node + 1];
    for (int p = p0; p < p1; ++p) {
        int s = csr_src[p];
        acc += di * dis[s] * H[(size_t)s * D + c];
    }
    out[(size_t)node * D + c] = acc + b[c];
}

// ---------------- launch ----------------

extern "C" void kernel_launch(void* const* d_in, const int* in_sizes, int n_in,
                              void* d_out, int out_size, void* d_ws, size_t ws_size,
                              hipStream_t stream) {
    const float* x  = (const float*)d_in[0];
    const int*   ei = (const int*)d_in[1];
    const float* W1 = (const float*)d_in[2];
    const float* b1 = (const float*)d_in[3];
    const float* W2 = (const float*)d_in[4];
    const float* b2 = (const float*)d_in[5];
    const float* W3 = (const float*)d_in[6];
    const float* b3 = (const float*)d_in[7];
    float* out = (float*)d_out;

    int n = in_sizes[0] / D;
    int E = in_sizes[1] / 2;
    const int* src = ei;
    const int* dst = ei + E;

    char* ws = (char*)d_ws;
    float* bufA   = (float*)ws; ws += (size_t)n * D * sizeof(float);
    int* cnt      = (int*)ws;   ws += (size_t)n * sizeof(int);
    float* dis    = (float*)ws; ws += (size_t)n * sizeof(float);
    int* row_ptr  = (int*)ws;   ws += (size_t)(n + 1) * sizeof(int);
    int* row_cur  = (int*)ws;   ws += (size_t)n * sizeof(int);
    int* csr_src  = (int*)ws;   ws += (size_t)E * sizeof(int);
    int* bsum     = (int*)ws;   ws += 1024 * sizeof(int);

    int gN = (n + 255) / 256;       // 391
    int gE = (E + 255) / 256;       // 6250
    int gM = (n + 127) / 128;       // 782

    // CSR build (per call; ws is re-poisoned every launch)
    zero_int<<<gN, 256, 0, stream>>>(cnt, n);
    hist_kernel<<<gE, 256, 0, stream>>>(dst, cnt, E);
    dis_kernel<<<gN, 256, 0, stream>>>(cnt, dis, n);
    scan1_kernel<<<gN, 256, 0, stream>>>(cnt, row_ptr, bsum, n);
    scan2_kernel<<<1, 512, 0, stream>>>(bsum, gN);
    scan3_kernel<<<gN, 256, 0, stream>>>(row_ptr, row_cur, bsum, n, E);
    scatter_kernel<<<gE, 256, 0, stream>>>(src, dst, row_cur, csr_src, E);

    // Layer 1: H = x@W1 -> bufA ; agg+b1 -> out
    gemm_kernel<false><<<gM, 256, 0, stream>>>(x, W1, bufA, n);
    aggregate_kernel<<<n, 128, 0, stream>>>(bufA, row_ptr, csr_src, dis, b1, out, n);
    // Layer 2: H = relu(out)@W2 -> bufA ; agg+b2 -> out
    gemm_kernel<true><<<gM, 256, 0, stream>>>(out, W2, bufA, n);
    aggregate_kernel<<<n, 128, 0, stream>>>(bufA, row_ptr, csr_src, dis, b2, out, n);
    // Layer 3: H = relu(out)@W3 -> bufA ; agg+b3 -> out
    gemm_kernel<true><<<gM, 256, 0, stream>>>(out, W3, bufA, n);
    aggregate_kernel<<<n, 128, 0, stream>>>(bufA, row_ptr, csr_src, dis, b3, out, n);
}

// Round 2
// 839.493 us; speedup vs baseline: 1.2075x; 1.2075x over previous
//
#include <hip/hip_runtime.h>

#define D 128
#define TPAD 132

// ---------------- CSR build ----------------

__global__ __launch_bounds__(256) void zero_int(int* __restrict__ p, int n) {
    int i = blockIdx.x * 256 + threadIdx.x;
    if (i < n) p[i] = 0;
}

__global__ __launch_bounds__(256) void hist_kernel(const int* __restrict__ dst,
                                                   int* __restrict__ cnt, int E) {
    int e = blockIdx.x * 256 + threadIdx.x;
    if (e < E) atomicAdd(&cnt[dst[e]], 1);
}

__global__ __launch_bounds__(256) void dis_kernel(const int* __restrict__ cnt,
                                                  float* __restrict__ dis, int n) {
    int i = blockIdx.x * 256 + threadIdx.x;
    if (i < n) dis[i] = rsqrtf((float)(cnt[i] + 1));   // +1 self-loop; deg>=1 always
}

__global__ __launch_bounds__(256) void scan1_kernel(const int* __restrict__ cnt,
                                                    int* __restrict__ row_ptr,
                                                    int* __restrict__ bsum, int n) {
    __shared__ int sh[256];
    int t = threadIdx.x;
    int i = blockIdx.x * 256 + t;
    int v = (i < n) ? cnt[i] : 0;
    sh[t] = v;
    __syncthreads();
    for (int off = 1; off < 256; off <<= 1) {
        int add = (t >= off) ? sh[t - off] : 0;
        __syncthreads();
        sh[t] += add;
        __syncthreads();
    }
    if (i < n) row_ptr[i] = sh[t] - v;       // block-local exclusive
    if (t == 255) bsum[blockIdx.x] = sh[255];
}

__global__ __launch_bounds__(512) void scan2_kernel(int* __restrict__ bsum, int nb) {
    __shared__ int sh[512];
    int t = threadIdx.x;
    int v = (t < nb) ? bsum[t] : 0;
    sh[t] = v;
    __syncthreads();
    for (int off = 1; off < 512; off <<= 1) {
        int add = (t >= off) ? sh[t - off] : 0;
        __syncthreads();
        sh[t] += add;
        __syncthreads();
    }
    if (t < nb) bsum[t] = sh[t] - v;         // exclusive scan of block sums
}

// row_cur aliases cnt's buffer (cnt dead after scan1)
__global__ __launch_bounds__(256) void scan3_kernel(int* __restrict__ row_ptr,
                                                    int* __restrict__ row_cur,
                                                    const int* __restrict__ bsum,
                                                    int n, int E) {
    int i = blockIdx.x * 256 + threadIdx.x;
    if (i < n) {
        int v = row_ptr[i] + bsum[blockIdx.x];
        row_ptr[i] = v;
        row_cur[i] = v;
    }
    if (i == 0) row_ptr[n] = E;
}

__global__ __launch_bounds__(256) void scatter_kernel(const int* __restrict__ src,
                                                      const int* __restrict__ dst,
                                                      int* __restrict__ row_cur,
                                                      int* __restrict__ csr_src, int E) {
    int e = blockIdx.x * 256 + threadIdx.x;
    if (e < E) {
        int d = dst[e];
        int pos = atomicAdd(&row_cur[d], 1);
        csr_src[pos] = src[e];
    }
}

// ---------------- GEMM: C[n x 128] = dis[row] * ((relu?)A[n x 128] @ W[128 x 128]) ----
// Row-scale fused into epilogue so aggregation needs no per-edge weights:
//   out[i] = dis_i * (H'[i] + sum_e H'[src_e]) + b   where H'[r] = dis_r * (A@W)[r]

template <bool RELU>
__global__ __launch_bounds__(256, 2) void gemm_kernel(const float* __restrict__ A,
                                                      const float* __restrict__ W,
                                                      const float* __restrict__ dis,
                                                      float* __restrict__ C, int n) {
    __shared__ float sAT[32 * TPAD];   // [k][r], 16.9 KB
    __shared__ float sW[32 * TPAD];    // [k][c], 16.9 KB
    int tid = threadIdx.x;
    int base = blockIdx.x * 128;
    int tx = tid & 15, ty = tid >> 4;

    float acc[8][8];
#pragma unroll
    for (int i = 0; i < 8; ++i)
#pragma unroll
        for (int j = 0; j < 8; ++j) acc[i][j] = 0.f;

    for (int kb = 0; kb < 128; kb += 32) {
        __syncthreads();   // protect previous chunk's reads
#pragma unroll
        for (int it = 0; it < 4; ++it) {
            int idx = it * 1024 + tid * 4;   // 0..4095
            // A: 128 rows x 32 ks, transposed store
            int r = idx >> 5, kk = idx & 31;
            int row = base + r;
            float4 va = make_float4(0.f, 0.f, 0.f, 0.f);
            if (row < n) va = *(const float4*)&A[row * D + kb + kk];
            if (RELU) {
                va.x = fmaxf(va.x, 0.f); va.y = fmaxf(va.y, 0.f);
                va.z = fmaxf(va.z, 0.f); va.w = fmaxf(va.w, 0.f);
            }
            sAT[(kk + 0) * TPAD + r] = va.x;
            sAT[(kk + 1) * TPAD + r] = va.y;
            sAT[(kk + 2) * TPAD + r] = va.z;
            sAT[(kk + 3) * TPAD + r] = va.w;
            // W: 32 ks x 128 cols, direct store
            int wk = idx >> 7, wc = idx & 127;
            *(float4*)&sW[wk * TPAD + wc] = *(const float4*)&W[(kb + wk) * D + wc];
        }
        __syncthreads();
#pragma unroll
        for (int k = 0; k < 32; ++k) {
            float4 a0 = *(const float4*)&sAT[k * TPAD + ty * 8];
            float4 a1 = *(const float4*)&sAT[k * TPAD + ty * 8 + 4];
            float4 w0 = *(const float4*)&sW[k * TPAD + tx * 8];
            float4 w1 = *(const float4*)&sW[k * TPAD + tx * 8 + 4];
            float a[8] = {a0.x, a0.y, a0.z, a0.w, a1.x, a1.y, a1.z, a1.w};
            float w[8] = {w0.x, w0.y, w0.z, w0.w, w1.x, w1.y, w1.z, w1.w};
#pragma unroll
            for (int i = 0; i < 8; ++i)
#pragma unroll
                for (int j = 0; j < 8; ++j) acc[i][j] = fmaf(a[i], w[j], acc[i][j]);
        }
    }

#pragma unroll
    for (int i = 0; i < 8; ++i) {
        int row = base + ty * 8 + i;
        if (row < n) {
            float di = dis[row];
            float4 o0 = make_float4(acc[i][0] * di, acc[i][1] * di,
                                    acc[i][2] * di, acc[i][3] * di);
            float4 o1 = make_float4(acc[i][4] * di, acc[i][5] * di,
                                    acc[i][6] * di, acc[i][7] * di);
            *(float4*)&C[row * D + tx * 8] = o0;
            *(float4*)&C[row * D + tx * 8 + 4] = o1;
        }
    }
}

// ---------------- Aggregation: out[i] = dis_i*(H'[i] + sum_e H'[src_e]) + b ----------
// One wave (64 lanes) per node, float2 per lane = 512 B per load instruction.
// Edge loop unrolled x4 -> 4 independent 512 B gathers in flight per wave.

__global__ __launch_bounds__(256) void aggregate_kernel(const float* __restrict__ Hs,
                                                        const int* __restrict__ row_ptr,
                                                        const int* __restrict__ csr_src,
                                                        const float* __restrict__ dis,
                                                        const float* __restrict__ b,
                                                        float* __restrict__ out, int n) {
    int node = blockIdx.x * 4 + (threadIdx.x >> 6);
    if (node >= n) return;
    int lane = threadIdx.x & 63;

    float2 h = ((const float2*)(Hs + (size_t)node * D))[lane];
    float accx = h.x, accy = h.y;                       // self-loop term H'[i]

    int p0 = row_ptr[node], p1 = row_ptr[node + 1];
    int p = p0;
    for (; p + 4 <= p1; p += 4) {
        int s0 = csr_src[p + 0];
        int s1 = csr_src[p + 1];
        int s2 = csr_src[p + 2];
        int s3 = csr_src[p + 3];
        float2 v0 = ((const float2*)(Hs + (size_t)s0 * D))[lane];
        float2 v1 = ((const float2*)(Hs + (size_t)s1 * D))[lane];
        float2 v2 = ((const float2*)(Hs + (size_t)s2 * D))[lane];
        float2 v3 = ((const float2*)(Hs + (size_t)s3 * D))[lane];
        accx += v0.x; accy += v0.y;
        accx += v1.x; accy += v1.y;
        accx += v2.x; accy += v2.y;
        accx += v3.x; accy += v3.y;
    }
    for (; p < p1; ++p) {
        int s = csr_src[p];
        float2 v = ((const float2*)(Hs + (size_t)s * D))[lane];
        accx += v.x; accy += v.y;
    }

    float di = dis[node];
    float2 bb = *(const float2*)(b + 2 * lane);
    float2 o;
    o.x = fmaf(accx, di, bb.x);
    o.y = fmaf(accy, di, bb.y);
    ((float2*)(out + (size_t)node * D))[lane] = o;
}

// ---------------- launch ----------------

extern "C" void kernel_launch(void* const* d_in, const int* in_sizes, int n_in,
                              void* d_out, int out_size, void* d_ws, size_t ws_size,
                              hipStream_t stream) {
    const float* x  = (const float*)d_in[0];
    const int*   ei = (const int*)d_in[1];
    const float* W1 = (const float*)d_in[2];
    const float* b1 = (const float*)d_in[3];
    const float* W2 = (const float*)d_in[4];
    const float* b2 = (const float*)d_in[5];
    const float* W3 = (const float*)d_in[6];
    const float* b3 = (const float*)d_in[7];
    float* out = (float*)d_out;

    int n = in_sizes[0] / D;
    int E = in_sizes[1] / 2;
    const int* src = ei;
    const int* dst = ei + E;

    char* ws = (char*)d_ws;
    float* bufA   = (float*)ws; ws += (size_t)n * D * sizeof(float);
    int* cnt      = (int*)ws;   ws += (size_t)n * sizeof(int);    // aliased as row_cur
    float* dis    = (float*)ws; ws += (size_t)n * sizeof(float);
    int* row_ptr  = (int*)ws;   ws += (size_t)(n + 1) * sizeof(int);
    int* csr_src  = (int*)ws;   ws += (size_t)E * sizeof(int);
    int* bsum     = (int*)ws;   ws += 1024 * sizeof(int);
    int* row_cur  = cnt;        // cnt is dead after scan1

    int gN = (n + 255) / 256;       // 391
    int gE = (E + 255) / 256;       // 6250
    int gM = (n + 127) / 128;       // 782
    int gA = (n + 3) / 4;           // 25000

    // CSR build (per call; ws is re-poisoned every launch)
    zero_int<<<gN, 256, 0, stream>>>(cnt, n);
    hist_kernel<<<gE, 256, 0, stream>>>(dst, cnt, E);
    dis_kernel<<<gN, 256, 0, stream>>>(cnt, dis, n);
    scan1_kernel<<<gN, 256, 0, stream>>>(cnt, row_ptr, bsum, n);
    scan2_kernel<<<1, 512, 0, stream>>>(bsum, gN);
    scan3_kernel<<<gN, 256, 0, stream>>>(row_ptr, row_cur, bsum, n, E);
    scatter_kernel<<<gE, 256, 0, stream>>>(src, dst, row_cur, csr_src, E);

    // Layer 1: H' = dis*(x@W1) -> bufA ; agg+b1 -> out
    gemm_kernel<false><<<gM, 256, 0, stream>>>(x, W1, dis, bufA, n);
    aggregate_kernel<<<gA, 256, 0, stream>>>(bufA, row_ptr, csr_src, dis, b1, out, n);
    // Layer 2: H' = dis*(relu(out)@W2) -> bufA ; agg+b2 -> out
    gemm_kernel<true><<<gM, 256, 0, stream>>>(out, W2, dis, bufA, n);
    aggregate_kernel<<<gA, 256, 0, stream>>>(bufA, row_ptr, csr_src, dis, b2, out, n);
    // Layer 3: H' = dis*(relu(out)@W3) -> bufA ; agg+b3 -> out
    gemm_kernel<true><<<gM, 256, 0, stream>>>(out, W3, dis, bufA, n);
    aggregate_kernel<<<gA, 256, 0, stream>>>(bufA, row_ptr, csr_src, dis, b3, out, n);
}

// Round 3
// 761.038 us; speedup vs baseline: 1.3320x; 1.1031x over previous
//
#include <hip/hip_runtime.h>

#define D 128
#define TPAD 132
#define NPB 256          // nodes per bucket (dst >> 8)
#define KMAX 512         // max buckets (n <= 131072)
#define CHUNK 4096       // edges per block in bucket passes

// ---------------- CSR build ----------------

__global__ __launch_bounds__(256) void zero_int(int* __restrict__ p, int n) {
    int i = blockIdx.x * 256 + threadIdx.x;
    if (i < n) p[i] = 0;
}

// Fused: degree histogram (cnt) + bucket histogram (bucket_cnt), one dst read.
__global__ __launch_bounds__(256) void hist2_kernel(const int* __restrict__ dst,
                                                    int* __restrict__ cnt,
                                                    int* __restrict__ bucket_cnt, int E) {
    __shared__ int scnt[KMAX];
    int t = threadIdx.x;
    for (int i = t; i < KMAX; i += 256) scnt[i] = 0;
    __syncthreads();
    int base = blockIdx.x * CHUNK;
    int nE = min(CHUNK, E - base);
    for (int i = t; i < nE; i += 256) {
        int d = dst[base + i];
        atomicAdd(&cnt[d], 1);
        atomicAdd(&scnt[d >> 8], 1);
    }
    __syncthreads();
    for (int i = t; i < KMAX; i += 256)
        if (scnt[i]) atomicAdd(&bucket_cnt[i], scnt[i]);
}

__global__ __launch_bounds__(256) void dis_kernel(const int* __restrict__ cnt,
                                                  float* __restrict__ dis, int n) {
    int i = blockIdx.x * 256 + threadIdx.x;
    if (i < n) dis[i] = rsqrtf((float)(cnt[i] + 1));   // +1 self-loop; deg>=1 always
}

// Exclusive scan of bucket_cnt[K] -> bucket_ptr[K+1], bucket_cur[K]=bucket_ptr[K]
__global__ __launch_bounds__(KMAX) void bucket_scan_kernel(const int* __restrict__ bucket_cnt,
                                                           int* __restrict__ bucket_ptr,
                                                           int* __restrict__ bucket_cur,
                                                           int K, int E) {
    __shared__ int sh[KMAX];
    int t = threadIdx.x;
    int v = (t < K) ? bucket_cnt[t] : 0;
    sh[t] = v;
    __syncthreads();
    for (int off = 1; off < KMAX; off <<= 1) {
        int add = (t >= off) ? sh[t - off] : 0;
        __syncthreads();
        sh[t] += add;
        __syncthreads();
    }
    if (t < K) {
        int ex = sh[t] - v;
        bucket_ptr[t] = ex;
        bucket_cur[t] = ex;
    }
    if (t == 0) bucket_ptr[K] = E;
}

__global__ __launch_bounds__(256) void scan1_kernel(const int* __restrict__ cnt,
                                                    int* __restrict__ row_ptr,
                                                    int* __restrict__ bsum, int n) {
    __shared__ int sh[256];
    int t = threadIdx.x;
    int i = blockIdx.x * 256 + t;
    int v = (i < n) ? cnt[i] : 0;
    sh[t] = v;
    __syncthreads();
    for (int off = 1; off < 256; off <<= 1) {
        int add = (t >= off) ? sh[t - off] : 0;
        __syncthreads();
        sh[t] += add;
        __syncthreads();
    }
    if (i < n) row_ptr[i] = sh[t] - v;       // block-local exclusive
    if (t == 255) bsum[blockIdx.x] = sh[255];
}

__global__ __launch_bounds__(512) void scan2_kernel(int* __restrict__ bsum, int nb) {
    __shared__ int sh[512];
    int t = threadIdx.x;
    int v = (t < nb) ? bsum[t] : 0;
    sh[t] = v;
    __syncthreads();
    for (int off = 1; off < 512; off <<= 1) {
        int add = (t >= off) ? sh[t - off] : 0;
        __syncthreads();
        sh[t] += add;
        __syncthreads();
    }
    if (t < nb) bsum[t] = sh[t] - v;         // exclusive scan of block sums
}

__global__ __launch_bounds__(256) void scan3_kernel(int* __restrict__ row_ptr,
                                                    const int* __restrict__ bsum,
                                                    int n, int E) {
    int i = blockIdx.x * 256 + threadIdx.x;
    if (i < n) row_ptr[i] += bsum[blockIdx.x];
    if (i == 0) row_ptr[n] = E;
}

// Phase A: partition edges into dst-buckets. Writes are contiguous runs per
// (block,bucket) -> near-full-line writebacks instead of 64B per 4B store.
__global__ __launch_bounds__(256) void bucket_scatter_kernel(const int* __restrict__ src,
                                                             const int* __restrict__ dst,
                                                             int* __restrict__ bucket_cur,
                                                             int2* __restrict__ bdata, int E) {
    __shared__ int sdst[CHUNK];     // 16 KB
    __shared__ int scnt[KMAX];      // 2 KB (counts, then local cursors)
    __shared__ int sbase[KMAX];     // 2 KB
    int t = threadIdx.x;
    int base = blockIdx.x * CHUNK;
    int nE = min(CHUNK, E - base);
    for (int i = t; i < KMAX; i += 256) scnt[i] = 0;
    __syncthreads();
    for (int i = t; i < nE; i += 256) {
        int d = dst[base + i];
        sdst[i] = d;
        atomicAdd(&scnt[d >> 8], 1);
    }
    __syncthreads();
    for (int i = t; i < KMAX; i += 256) {
        int c = scnt[i];
        sbase[i] = c ? atomicAdd(&bucket_cur[i], c) : 0;
        scnt[i] = 0;                // reuse as local cursor
    }
    __syncthreads();
    for (int i = t; i < nE; i += 256) {
        int d = sdst[i];
        int b = d >> 8;
        int pos = sbase[b] + atomicAdd(&scnt[b], 1);
        bdata[pos] = make_int2(src[base + i], d);
    }
}

// Phase B: one block per bucket owns a contiguous csr_src region exclusively;
// per-node cursors live in LDS (no global atomics, no cross-XCD ping-pong).
__global__ __launch_bounds__(256) void csr_from_buckets_kernel(const int2* __restrict__ bdata,
                                                               const int* __restrict__ bucket_ptr,
                                                               const int* __restrict__ row_ptr,
                                                               int* __restrict__ csr_src, int n) {
    __shared__ int cursor[NPB];
    int b = blockIdx.x;
    int node0 = b << 8;
    int nn = min(NPB, n - node0);
    int t = threadIdx.x;
    if (t < nn) cursor[t] = row_ptr[node0 + t];
    __syncthreads();
    int p0 = bucket_ptr[b], p1 = bucket_ptr[b + 1];
    for (int i = p0 + t; i < p1; i += 256) {
        int2 e = bdata[i];
        int pos = atomicAdd(&cursor[e.y - node0], 1);
        csr_src[pos] = e.x;
    }
}

// ---------------- GEMM: C[n x 128] = dis[row] * ((relu?)A[n x 128] @ W[128 x 128]) ----
// Row-scale fused into epilogue so aggregation needs no per-edge weights:
//   out[i] = dis_i * (H'[i] + sum_e H'[src_e]) + b   where H'[r] = dis_r * (A@W)[r]

template <bool RELU>
__global__ __launch_bounds__(256, 2) void gemm_kernel(const float* __restrict__ A,
                                                      const float* __restrict__ W,
                                                      const float* __restrict__ dis,
                                                      float* __restrict__ C, int n) {
    __shared__ float sAT[32 * TPAD];   // [k][r], 16.9 KB
    __shared__ float sW[32 * TPAD];    // [k][c], 16.9 KB
    int tid = threadIdx.x;
    int base = blockIdx.x * 128;
    int tx = tid & 15, ty = tid >> 4;

    float acc[8][8];
#pragma unroll
    for (int i = 0; i < 8; ++i)
#pragma unroll
        for (int j = 0; j < 8; ++j) acc[i][j] = 0.f;

    for (int kb = 0; kb < 128; kb += 32) {
        __syncthreads();   // protect previous chunk's reads
#pragma unroll
        for (int it = 0; it < 4; ++it) {
            int idx = it * 1024 + tid * 4;   // 0..4095
            int r = idx >> 5, kk = idx & 31;
            int row = base + r;
            float4 va = make_float4(0.f, 0.f, 0.f, 0.f);
            if (row < n) va = *(const float4*)&A[row * D + kb + kk];
            if (RELU) {
                va.x = fmaxf(va.x, 0.f); va.y = fmaxf(va.y, 0.f);
                va.z = fmaxf(va.z, 0.f); va.w = fmaxf(va.w, 0.f);
            }
            sAT[(kk + 0) * TPAD + r] = va.x;
            sAT[(kk + 1) * TPAD + r] = va.y;
            sAT[(kk + 2) * TPAD + r] = va.z;
            sAT[(kk + 3) * TPAD + r] = va.w;
            int wk = idx >> 7, wc = idx & 127;
            *(float4*)&sW[wk * TPAD + wc] = *(const float4*)&W[(kb + wk) * D + wc];
        }
        __syncthreads();
#pragma unroll
        for (int k = 0; k < 32; ++k) {
            float4 a0 = *(const float4*)&sAT[k * TPAD + ty * 8];
            float4 a1 = *(const float4*)&sAT[k * TPAD + ty * 8 + 4];
            float4 w0 = *(const float4*)&sW[k * TPAD + tx * 8];
            float4 w1 = *(const float4*)&sW[k * TPAD + tx * 8 + 4];
            float a[8] = {a0.x, a0.y, a0.z, a0.w, a1.x, a1.y, a1.z, a1.w};
            float w[8] = {w0.x, w0.y, w0.z, w0.w, w1.x, w1.y, w1.z, w1.w};
#pragma unroll
            for (int i = 0; i < 8; ++i)
#pragma unroll
                for (int j = 0; j < 8; ++j) acc[i][j] = fmaf(a[i], w[j], acc[i][j]);
        }
    }

#pragma unroll
    for (int i = 0; i < 8; ++i) {
        int row = base + ty * 8 + i;
        if (row < n) {
            float di = dis[row];
            float4 o0 = make_float4(acc[i][0] * di, acc[i][1] * di,
                                    acc[i][2] * di, acc[i][3] * di);
            float4 o1 = make_float4(acc[i][4] * di, acc[i][5] * di,
                                    acc[i][6] * di, acc[i][7] * di);
            *(float4*)&C[row * D + tx * 8] = o0;
            *(float4*)&C[row * D + tx * 8 + 4] = o1;
        }
    }
}

// ---------------- Aggregation: out[i] = dis_i*(H'[i] + sum_e H'[src_e]) + b ----------

__global__ __launch_bounds__(256) void aggregate_kernel(const float* __restrict__ Hs,
                                                        const int* __restrict__ row_ptr,
                                                        const int* __restrict__ csr_src,
                                                        const float* __restrict__ dis,
                                                        const float* __restrict__ b,
                                                        float* __restrict__ out, int n) {
    int node = blockIdx.x * 4 + (threadIdx.x >> 6);
    if (node >= n) return;
    int lane = threadIdx.x & 63;

    float2 h = ((const float2*)(Hs + (size_t)node * D))[lane];
    float accx = h.x, accy = h.y;                       // self-loop term H'[i]

    int p0 = row_ptr[node], p1 = row_ptr[node + 1];
    int p = p0;
    for (; p + 4 <= p1; p += 4) {
        int s0 = csr_src[p + 0];
        int s1 = csr_src[p + 1];
        int s2 = csr_src[p + 2];
        int s3 = csr_src[p + 3];
        float2 v0 = ((const float2*)(Hs + (size_t)s0 * D))[lane];
        float2 v1 = ((const float2*)(Hs + (size_t)s1 * D))[lane];
        float2 v2 = ((const float2*)(Hs + (size_t)s2 * D))[lane];
        float2 v3 = ((const float2*)(Hs + (size_t)s3 * D))[lane];
        accx += v0.x; accy += v0.y;
        accx += v1.x; accy += v1.y;
        accx += v2.x; accy += v2.y;
        accx += v3.x; accy += v3.y;
    }
    for (; p < p1; ++p) {
        int s = csr_src[p];
        float2 v = ((const float2*)(Hs + (size_t)s * D))[lane];
        accx += v.x; accy += v.y;
    }

    float di = dis[node];
    float2 bb = *(const float2*)(b + 2 * lane);
    float2 o;
    o.x = fmaf(accx, di, bb.x);
    o.y = fmaf(accy, di, bb.y);
    ((float2*)(out + (size_t)node * D))[lane] = o;
}

// ---------------- launch ----------------

extern "C" void kernel_launch(void* const* d_in, const int* in_sizes, int n_in,
                              void* d_out, int out_size, void* d_ws, size_t ws_size,
                              hipStream_t stream) {
    const float* x  = (const float*)d_in[0];
    const int*   ei = (const int*)d_in[1];
    const float* W1 = (const float*)d_in[2];
    const float* b1 = (const float*)d_in[3];
    const float* W2 = (const float*)d_in[4];
    const float* b2 = (const float*)d_in[5];
    const float* W3 = (const float*)d_in[6];
    const float* b3 = (const float*)d_in[7];
    float* out = (float*)d_out;

    int n = in_sizes[0] / D;
    int E = in_sizes[1] / 2;
    const int* src = ei;
    const int* dst = ei + E;
    int K = (n + NPB - 1) >> 8;     // buckets

    char* ws = (char*)d_ws;
    float* bufA      = (float*)ws; ws += (size_t)n * D * sizeof(float);
    int* cnt         = (int*)ws;   ws += (size_t)n * sizeof(int);
    float* dis       = (float*)ws; ws += (size_t)n * sizeof(float);
    int* row_ptr     = (int*)ws;   ws += (size_t)(n + 1) * sizeof(int);
    int* csr_src     = (int*)ws;   ws += (size_t)E * sizeof(int);
    int* bsum        = (int*)ws;   ws += 1024 * sizeof(int);
    int* bucket_cnt  = (int*)ws;   ws += KMAX * sizeof(int);
    int* bucket_ptr  = (int*)ws;   ws += (KMAX + 1) * sizeof(int);
    int* bucket_cur  = (int*)ws;   ws += KMAX * sizeof(int);
    int2* bdata      = (int2*)bufA;   // aliases bufA; dead before first GEMM writes it

    int gN = (n + 255) / 256;         // 391
    int gC = (E + CHUNK - 1) / CHUNK; // 391
    int gM = (n + 127) / 128;         // 782
    int gA = (n + 3) / 4;             // 25000

    // CSR build (per call; ws is re-poisoned every launch)
    zero_int<<<gN + 2, 256, 0, stream>>>(cnt, n);                 // covers cnt
    zero_int<<<2, 256, 0, stream>>>(bucket_cnt, KMAX);
    hist2_kernel<<<gC, 256, 0, stream>>>(dst, cnt, bucket_cnt, E);
    dis_kernel<<<gN, 256, 0, stream>>>(cnt, dis, n);
    bucket_scan_kernel<<<1, KMAX, 0, stream>>>(bucket_cnt, bucket_ptr, bucket_cur, K, E);
    scan1_kernel<<<gN, 256, 0, stream>>>(cnt, row_ptr, bsum, n);
    scan2_kernel<<<1, 512, 0, stream>>>(bsum, gN);
    scan3_kernel<<<gN, 256, 0, stream>>>(row_ptr, bsum, n, E);
    bucket_scatter_kernel<<<gC, 256, 0, stream>>>(src, dst, bucket_cur, bdata, E);
    csr_from_buckets_kernel<<<K, 256, 0, stream>>>(bdata, bucket_ptr, row_ptr, csr_src, n);

    // Layer 1: H' = dis*(x@W1) -> bufA ; agg+b1 -> out
    gemm_kernel<false><<<gM, 256, 0, stream>>>(x, W1, dis, bufA, n);
    aggregate_kernel<<<gA, 256, 0, stream>>>(bufA, row_ptr, csr_src, dis, b1, out, n);
    // Layer 2: H' = dis*(relu(out)@W2) -> bufA ; agg+b2 -> out
    gemm_kernel<true><<<gM, 256, 0, stream>>>(out, W2, dis, bufA, n);
    aggregate_kernel<<<gA, 256, 0, stream>>>(bufA, row_ptr, csr_src, dis, b2, out, n);
    // Layer 3: H' = dis*(relu(out)@W3) -> bufA ; agg+b3 -> out
    gemm_kernel<true><<<gM, 256, 0, stream>>>(out, W3, dis, bufA, n);
    aggregate_kernel<<<gA, 256, 0, stream>>>(bufA, row_ptr, csr_src, dis, b3, out, n);
}

// Round 4
// 712.729 us; speedup vs baseline: 1.4223x; 1.0678x over previous
//
#include <hip/hip_runtime.h>

#define D 128
#define TPAD 132
#define NPB 256          // nodes per bucket (dst >> 8)
#define KMAX 512         // max buckets (n <= 131072)
#define CHUNK 4096       // edges per block in bucket passes

// ---------------- CSR build ----------------
// No per-node global atomics anywhere: bucket histogram is LDS-aggregated over
// 512 counters; per-node counts/offsets are derived per-bucket in LDS.

__global__ __launch_bounds__(256) void zero_int(int* __restrict__ p, int n) {
    int i = blockIdx.x * 256 + threadIdx.x;
    if (i < n) p[i] = 0;
}

__global__ __launch_bounds__(256) void bucket_hist_kernel(const int* __restrict__ dst,
                                                          int* __restrict__ bucket_cnt, int E) {
    __shared__ int scnt[KMAX];
    int t = threadIdx.x;
    for (int i = t; i < KMAX; i += 256) scnt[i] = 0;
    __syncthreads();
    int base = blockIdx.x * CHUNK;
    int nE = min(CHUNK, E - base);
    for (int i = t; i < nE; i += 256)
        atomicAdd(&scnt[dst[base + i] >> 8], 1);
    __syncthreads();
    for (int i = t; i < KMAX; i += 256)
        if (scnt[i]) atomicAdd(&bucket_cnt[i], scnt[i]);
}

// Exclusive scan of bucket_cnt[K] -> bucket_ptr[K+1], bucket_cur[K]=bucket_ptr[K]
__global__ __launch_bounds__(KMAX) void bucket_scan_kernel(const int* __restrict__ bucket_cnt,
                                                           int* __restrict__ bucket_ptr,
                                                           int* __restrict__ bucket_cur,
                                                           int K, int E) {
    __shared__ int sh[KMAX];
    int t = threadIdx.x;
    int v = (t < K) ? bucket_cnt[t] : 0;
    sh[t] = v;
    __syncthreads();
    for (int off = 1; off < KMAX; off <<= 1) {
        int add = (t >= off) ? sh[t - off] : 0;
        __syncthreads();
        sh[t] += add;
        __syncthreads();
    }
    if (t < K) {
        int ex = sh[t] - v;
        bucket_ptr[t] = ex;
        bucket_cur[t] = ex;
    }
    if (t == 0) bucket_ptr[K] = E;
}

// Phase A: partition edges into dst-buckets. Writes are contiguous runs per
// (block,bucket) -> near-full-line writebacks instead of 64B per 4B store.
__global__ __launch_bounds__(256) void bucket_scatter_kernel(const int* __restrict__ src,
                                                             const int* __restrict__ dst,
                                                             int* __restrict__ bucket_cur,
                                                             int2* __restrict__ bdata, int E) {
    __shared__ int sdst[CHUNK];     // 16 KB
    __shared__ int scnt[KMAX];      // 2 KB (counts, then local cursors)
    __shared__ int sbase[KMAX];     // 2 KB
    int t = threadIdx.x;
    int base = blockIdx.x * CHUNK;
    int nE = min(CHUNK, E - base);
    for (int i = t; i < KMAX; i += 256) scnt[i] = 0;
    __syncthreads();
    for (int i = t; i < nE; i += 256) {
        int d = dst[base + i];
        sdst[i] = d;
        atomicAdd(&scnt[d >> 8], 1);
    }
    __syncthreads();
    for (int i = t; i < KMAX; i += 256) {
        int c = scnt[i];
        sbase[i] = c ? atomicAdd(&bucket_cur[i], c) : 0;
        scnt[i] = 0;                // reuse as local cursor
    }
    __syncthreads();
    for (int i = t; i < nE; i += 256) {
        int d = sdst[i];
        int b = d >> 8;
        int pos = sbase[b] + atomicAdd(&scnt[b], 1);
        bdata[pos] = make_int2(src[base + i], d);
    }
}

// Per-bucket: LDS histogram of dst -> per-node count; LDS exclusive scan gives
// row_ptr[node] = bucket_ptr[b] + scan (buckets are contiguous dst ranges, so
// this IS the global CSR offset — no global scan chain needed). Also emits dis.
__global__ __launch_bounds__(256) void csr_count_scan_kernel(const int2* __restrict__ bdata,
                                                             const int* __restrict__ bucket_ptr,
                                                             int* __restrict__ row_ptr,
                                                             float* __restrict__ dis,
                                                             int n, int E, int K) {
    __shared__ int scnt[NPB];
    __shared__ int sh[NPB];
    int b = blockIdx.x;
    int node0 = b << 8;
    int nn = min(NPB, n - node0);
    int t = threadIdx.x;
    scnt[t] = 0;
    __syncthreads();
    int p0 = bucket_ptr[b], p1 = bucket_ptr[b + 1];
    for (int i = p0 + t; i < p1; i += 256)
        atomicAdd(&scnt[bdata[i].y - node0], 1);
    __syncthreads();
    int v = scnt[t];
    sh[t] = v;
    __syncthreads();
    for (int off = 1; off < NPB; off <<= 1) {
        int add = (t >= off) ? sh[t - off] : 0;
        __syncthreads();
        sh[t] += add;
        __syncthreads();
    }
    if (t < nn) {
        row_ptr[node0 + t] = p0 + sh[t] - v;     // exclusive
        dis[node0 + t] = rsqrtf((float)(v + 1)); // +1 self-loop
    }
    if (b == K - 1 && t == 0) row_ptr[n] = E;
}

// Phase B: one block per bucket owns a contiguous csr_src region exclusively;
// per-node cursors live in LDS (no global atomics, no cross-XCD ping-pong).
__global__ __launch_bounds__(256) void csr_fill_kernel(const int2* __restrict__ bdata,
                                                       const int* __restrict__ bucket_ptr,
                                                       const int* __restrict__ row_ptr,
                                                       int* __restrict__ csr_src, int n) {
    __shared__ int cursor[NPB];
    int b = blockIdx.x;
    int node0 = b << 8;
    int nn = min(NPB, n - node0);
    int t = threadIdx.x;
    if (t < nn) cursor[t] = row_ptr[node0 + t];
    __syncthreads();
    int p0 = bucket_ptr[b], p1 = bucket_ptr[b + 1];
    for (int i = p0 + t; i < p1; i += 256) {
        int2 e = bdata[i];
        int pos = atomicAdd(&cursor[e.y - node0], 1);
        csr_src[pos] = e.x;
    }
}

// ---------------- GEMM: C[n x 128] = dis[row] * ((relu?)A[n x 128] @ W[128 x 128]) ----
// Row-scale fused into epilogue so aggregation needs no per-edge weights:
//   out[i] = dis_i * (H'[i] + sum_e H'[src_e]) + b   where H'[r] = dis_r * (A@W)[r]

template <bool RELU>
__global__ __launch_bounds__(256, 2) void gemm_kernel(const float* __restrict__ A,
                                                      const float* __restrict__ W,
                                                      const float* __restrict__ dis,
                                                      float* __restrict__ C, int n) {
    __shared__ float sAT[32 * TPAD];   // [k][r], 16.9 KB
    __shared__ float sW[32 * TPAD];    // [k][c], 16.9 KB
    int tid = threadIdx.x;
    int base = blockIdx.x * 128;
    int tx = tid & 15, ty = tid >> 4;

    float acc[8][8];
#pragma unroll
    for (int i = 0; i < 8; ++i)
#pragma unroll
        for (int j = 0; j < 8; ++j) acc[i][j] = 0.f;

    for (int kb = 0; kb < 128; kb += 32) {
        __syncthreads();   // protect previous chunk's reads
#pragma unroll
        for (int it = 0; it < 4; ++it) {
            int idx = it * 1024 + tid * 4;   // 0..4095
            int r = idx >> 5, kk = idx & 31;
            int row = base + r;
            float4 va = make_float4(0.f, 0.f, 0.f, 0.f);
            if (row < n) va = *(const float4*)&A[row * D + kb + kk];
            if (RELU) {
                va.x = fmaxf(va.x, 0.f); va.y = fmaxf(va.y, 0.f);
                va.z = fmaxf(va.z, 0.f); va.w = fmaxf(va.w, 0.f);
            }
            sAT[(kk + 0) * TPAD + r] = va.x;
            sAT[(kk + 1) * TPAD + r] = va.y;
            sAT[(kk + 2) * TPAD + r] = va.z;
            sAT[(kk + 3) * TPAD + r] = va.w;
            int wk = idx >> 7, wc = idx & 127;
            *(float4*)&sW[wk * TPAD + wc] = *(const float4*)&W[(kb + wk) * D + wc];
        }
        __syncthreads();
#pragma unroll
        for (int k = 0; k < 32; ++k) {
            float4 a0 = *(const float4*)&sAT[k * TPAD + ty * 8];
            float4 a1 = *(const float4*)&sAT[k * TPAD + ty * 8 + 4];
            float4 w0 = *(const float4*)&sW[k * TPAD + tx * 8];
            float4 w1 = *(const float4*)&sW[k * TPAD + tx * 8 + 4];
            float a[8] = {a0.x, a0.y, a0.z, a0.w, a1.x, a1.y, a1.z, a1.w};
            float w[8] = {w0.x, w0.y, w0.z, w0.w, w1.x, w1.y, w1.z, w1.w};
#pragma unroll
            for (int i = 0; i < 8; ++i)
#pragma unroll
                for (int j = 0; j < 8; ++j) acc[i][j] = fmaf(a[i], w[j], acc[i][j]);
        }
    }

#pragma unroll
    for (int i = 0; i < 8; ++i) {
        int row = base + ty * 8 + i;
        if (row < n) {
            float di = dis[row];
            float4 o0 = make_float4(acc[i][0] * di, acc[i][1] * di,
                                    acc[i][2] * di, acc[i][3] * di);
            float4 o1 = make_float4(acc[i][4] * di, acc[i][5] * di,
                                    acc[i][6] * di, acc[i][7] * di);
            *(float4*)&C[row * D + tx * 8] = o0;
            *(float4*)&C[row * D + tx * 8 + 4] = o1;
        }
    }
}

// ---------------- Aggregation: out[i] = dis_i*(H'[i] + sum_e H'[src_e]) + b ----------

__global__ __launch_bounds__(256) void aggregate_kernel(const float* __restrict__ Hs,
                                                        const int* __restrict__ row_ptr,
                                                        const int* __restrict__ csr_src,
                                                        const float* __restrict__ dis,
                                                        const float* __restrict__ b,
                                                        float* __restrict__ out, int n) {
    int node = blockIdx.x * 4 + (threadIdx.x >> 6);
    if (node >= n) return;
    int lane = threadIdx.x & 63;

    float2 h = ((const float2*)(Hs + (size_t)node * D))[lane];
    float accx = h.x, accy = h.y;                       // self-loop term H'[i]

    int p0 = row_ptr[node], p1 = row_ptr[node + 1];
    int p = p0;
    for (; p + 4 <= p1; p += 4) {
        int s0 = csr_src[p + 0];
        int s1 = csr_src[p + 1];
        int s2 = csr_src[p + 2];
        int s3 = csr_src[p + 3];
        float2 v0 = ((const float2*)(Hs + (size_t)s0 * D))[lane];
        float2 v1 = ((const float2*)(Hs + (size_t)s1 * D))[lane];
        float2 v2 = ((const float2*)(Hs + (size_t)s2 * D))[lane];
        float2 v3 = ((const float2*)(Hs + (size_t)s3 * D))[lane];
        accx += v0.x; accy += v0.y;
        accx += v1.x; accy += v1.y;
        accx += v2.x; accy += v2.y;
        accx += v3.x; accy += v3.y;
    }
    for (; p < p1; ++p) {
        int s = csr_src[p];
        float2 v = ((const float2*)(Hs + (size_t)s * D))[lane];
        accx += v.x; accy += v.y;
    }

    float di = dis[node];
    float2 bb = *(const float2*)(b + 2 * lane);
    float2 o;
    o.x = fmaf(accx, di, bb.x);
    o.y = fmaf(accy, di, bb.y);
    ((float2*)(out + (size_t)node * D))[lane] = o;
}

// ---------------- launch ----------------

extern "C" void kernel_launch(void* const* d_in, const int* in_sizes, int n_in,
                              void* d_out, int out_size, void* d_ws, size_t ws_size,
                              hipStream_t stream) {
    const float* x  = (const float*)d_in[0];
    const int*   ei = (const int*)d_in[1];
    const float* W1 = (const float*)d_in[2];
    const float* b1 = (const float*)d_in[3];
    const float* W2 = (const float*)d_in[4];
    const float* b2 = (const float*)d_in[5];
    const float* W3 = (const float*)d_in[6];
    const float* b3 = (const float*)d_in[7];
    float* out = (float*)d_out;

    int n = in_sizes[0] / D;
    int E = in_sizes[1] / 2;
    const int* src = ei;
    const int* dst = ei + E;
    int K = (n + NPB - 1) >> 8;     // buckets

    char* ws = (char*)d_ws;
    float* bufA      = (float*)ws; ws += (size_t)n * D * sizeof(float);
    float* dis       = (float*)ws; ws += (size_t)n * sizeof(float);
    int* row_ptr     = (int*)ws;   ws += (size_t)(n + 1) * sizeof(int);
    int* csr_src     = (int*)ws;   ws += (size_t)E * sizeof(int);
    int* bucket_cnt  = (int*)ws;   ws += KMAX * sizeof(int);
    int* bucket_ptr  = (int*)ws;   ws += (KMAX + 1) * sizeof(int);
    int* bucket_cur  = (int*)ws;   ws += KMAX * sizeof(int);
    int2* bdata      = (int2*)bufA;   // aliases bufA; dead before first GEMM writes it

    int gC = (E + CHUNK - 1) / CHUNK; // 391
    int gM = (n + 127) / 128;         // 782
    int gA = (n + 3) / 4;             // 25000

    // CSR build — no per-node global atomics anywhere.
    zero_int<<<2, 256, 0, stream>>>(bucket_cnt, KMAX);
    bucket_hist_kernel<<<gC, 256, 0, stream>>>(dst, bucket_cnt, E);
    bucket_scan_kernel<<<1, KMAX, 0, stream>>>(bucket_cnt, bucket_ptr, bucket_cur, K, E);
    bucket_scatter_kernel<<<gC, 256, 0, stream>>>(src, dst, bucket_cur, bdata, E);
    csr_count_scan_kernel<<<K, 256, 0, stream>>>(bdata, bucket_ptr, row_ptr, dis, n, E, K);
    csr_fill_kernel<<<K, 256, 0, stream>>>(bdata, bucket_ptr, row_ptr, csr_src, n);

    // Layer 1: H' = dis*(x@W1) -> bufA ; agg+b1 -> out
    gemm_kernel<false><<<gM, 256, 0, stream>>>(x, W1, dis, bufA, n);
    aggregate_kernel<<<gA, 256, 0, stream>>>(bufA, row_ptr, csr_src, dis, b1, out, n);
    // Layer 2: H' = dis*(relu(out)@W2) -> bufA ; agg+b2 -> out
    gemm_kernel<true><<<gM, 256, 0, stream>>>(out, W2, dis, bufA, n);
    aggregate_kernel<<<gA, 256, 0, stream>>>(bufA, row_ptr, csr_src, dis, b2, out, n);
    // Layer 3: H' = dis*(relu(out)@W3) -> bufA ; agg+b3 -> out
    gemm_kernel<true><<<gM, 256, 0, stream>>>(out, W3, dis, bufA, n);
    aggregate_kernel<<<gA, 256, 0, stream>>>(bufA, row_ptr, csr_src, dis, b3, out, n);
}